// Round 19
// baseline (97.899 us; speedup 1.0000x reference)
//
#include <hip/hip_runtime.h>
#include <stdint.h>

#define SEQ 3072
#define NH  16
#define DH  64
#define WQ  32
#define KVBLK 64
#define NKT (SEQ / KVBLK)    // 48
#define QUART_T (NKT / 4)    // 12 (even)
#define NQT (SEQ / WQ)       // 96
#define NWORDS (SEQ * SEQ / 64)

typedef __attribute__((ext_vector_type(8))) __bf16 bf16x8;
typedef __attribute__((ext_vector_type(16))) float f32x16;

union BF8 { ushort us[8]; uint u[4]; uint4 u4; bf16x8 v; };

__device__ __forceinline__ ushort f2bf(float f) {
    uint u = __builtin_bit_cast(uint, f);
    return (ushort)((u + 0x7FFFu + ((u >> 16) & 1u)) >> 16);
}

// ---------------- mask dtype detection ----------------
__global__ void detect_kernel(const uint32_t* __restrict__ m, int* __restrict__ flag) {
    __shared__ int cntA, cntB;
    if (threadIdx.x == 0) { cntA = 0; cntB = 0; }
    __syncthreads();
    int a = 0, b = 0;
    for (int i = 0; i < 16; ++i) {
        uint32_t w = m[threadIdx.x + i * 256];
        if (w & 0xFFFFFF00u) a = 1;
        if (w & 0x0000FFFFu) b = 1;
    }
    if (a) atomicOr(&cntA, 1);
    if (b) atomicOr(&cntB, 1);
    __syncthreads();
    if (threadIdx.x == 0) *flag = (cntA == 0) ? 1 : ((cntB == 0) ? 2 : 0);
}

#define SCALE_Q (0.125f * 1.44269504f)

// ---------------- fused pre-pass: convert_kv (768) + convert_q (256) + pack (1024) ----
__global__ __launch_bounds__(256)
void fused_prep(const float* __restrict__ K, const float* __restrict__ V,
                const float* __restrict__ Q, const void* __restrict__ mask,
                const int* __restrict__ flag,
                ushort* __restrict__ Kbz, ushort* __restrict__ Vtz,
                ushort* __restrict__ Qb, uint64_t* __restrict__ bits)
{
    const int b = blockIdx.x;
    const int tid = threadIdx.x;

    if (b < 768) {
        // ---------- convert_kv (per-lane fragment order, R12-verified) ----------
        const int kt = b % NKT, h = b / NKT;
        __shared__ float Vf[64][68];
        {
            const int kr = tid >> 2, dc = (tid & 3) * 16;
            const float* vsrc = V + (((size_t)(kt * KVBLK + kr) * NH + h) * DH + dc);
            #pragma unroll
            for (int j = 0; j < 4; ++j) {
                float4 t = *(const float4*)(vsrc + 4 * j);
                Vf[kr][dc + 4 * j + 0] = t.x; Vf[kr][dc + 4 * j + 1] = t.y;
                Vf[kr][dc + 4 * j + 2] = t.z; Vf[kr][dc + 4 * j + 3] = t.w;
            }
        }

        ushort* kout = Kbz + ((size_t)(h * NKT + kt)) * 4096;
        #pragma unroll
        for (int i = 0; i < 2; ++i) {
            const int idx = tid + 256 * i;          // 0..511 = f*64 + l
            const int f = idx >> 6, l = idx & 63;
            const int kc = f >> 1, kh = f & 1;
            const int row = kh * 32 + (l & 31);
            const int kcol = kc * 16 + (l >> 5) * 8;
            const float* ks = K + (((size_t)(kt * KVBLK + row) * NH + h) * DH + kcol);
            float4 a = *(const float4*)(ks);
            float4 c = *(const float4*)(ks + 4);
            BF8 t;
            t.us[0] = f2bf(a.x); t.us[1] = f2bf(a.y); t.us[2] = f2bf(a.z); t.us[3] = f2bf(a.w);
            t.us[4] = f2bf(c.x); t.us[5] = f2bf(c.y); t.us[6] = f2bf(c.z); t.us[7] = f2bf(c.w);
            *(uint4*)(kout + idx * 8) = t.u4;
        }

        __syncthreads();

        ushort* vout = Vtz + ((size_t)(h * NKT + kt)) * 4096;
        #pragma unroll
        for (int i = 0; i < 2; ++i) {
            const int idx = tid + 256 * i;
            const int f = idx >> 6, l = idx & 63;
            const int kc = f >> 1, dh = f & 1;
            const int d = dh * 32 + (l & 31);
            const int kr0 = kc * 16 + (l >> 5) * 8;
            BF8 t;
            #pragma unroll
            for (int j = 0; j < 8; ++j)
                t.us[j] = f2bf(Vf[kr0 + j][d]);
            *(uint4*)(vout + idx * 8) = t.u4;
        }
    } else if (b < 1024) {
        // ---------- convert_q (grid-stride) ----------
        for (int vb = b - 768; vb < SEQ * NH * DH / (256 * 8); vb += 256) {
            int i = (vb * 256 + tid) * 8;
            float4 a = *(const float4*)(Q + i);
            float4 c = *(const float4*)(Q + i + 4);
            BF8 t;
            t.us[0] = f2bf(a.x * SCALE_Q); t.us[1] = f2bf(a.y * SCALE_Q);
            t.us[2] = f2bf(a.z * SCALE_Q); t.us[3] = f2bf(a.w * SCALE_Q);
            t.us[4] = f2bf(c.x * SCALE_Q); t.us[5] = f2bf(c.y * SCALE_Q);
            t.us[6] = f2bf(c.z * SCALE_Q); t.us[7] = f2bf(c.w * SCALE_Q);
            *(uint4*)(Qb + i) = t.u4;
        }
    } else {
        // ---------- pack -> bits2[kword*SEQ + qrow] (grid-stride) ----------
        const int f = *flag;
        for (int vb = b - 1024; vb < SEQ * SEQ / 256; vb += 1024) {
            const int g = vb * 256 + tid;
            bool v;
            if (f == 1)      v = ((const int*)mask)[g] != 0;
            else if (f == 2) v = ((const float*)mask)[g] != 0.0f;
            else             v = ((const unsigned char*)mask)[g] != 0;
            uint64_t bl = __ballot(v);
            if ((tid & 63) == 0) {
                int w = g >> 6;
                int qrow = w / NKT, cw = w % NKT;
                bits[(size_t)cw * SEQ + qrow] = bl;
            }
        }
    }
}

// ---------------- fragment load: global (L2) -> VGPR, no LDS ----------------
__device__ __forceinline__ bf16x8 ldfrag(const ushort* tile, int f, int lane) {
    return *(const bf16x8*)(tile + f * 512 + lane * 8);
}

// ---------------- per-tile math (R10/R12/R16 verified path) ----------------
__device__ __forceinline__ void process_tile(
    const bf16x8 kf[8], const bf16x8 vf[8], const bf16x8 qf[4],
    uint64_t mw, int hh, f32x16& o0, f32x16& o1, float& l_)
{
    const uint64_t mu = mw >> (4 * hh);
    const uint mlo = (uint)mu, mhi = (uint)(mu >> 32);
    f32x16 s0, s1;
    #pragma unroll
    for (int r = 0; r < 16; ++r) {
        const int sh = (r & 3) + 8 * (r >> 2);
        const uint b0 = (mlo >> sh) & 1u;
        const uint b1 = (mhi >> sh) & 1u;
        s0[r] = __builtin_bit_cast(float, (b0 - 1u) & 0xFF800000u);
        s1[r] = __builtin_bit_cast(float, (b1 - 1u) & 0xFF800000u);
    }

    __builtin_amdgcn_s_setprio(1);
    #pragma unroll
    for (int kc = 0; kc < 4; ++kc) {
        s0 = __builtin_amdgcn_mfma_f32_32x32x16_bf16(kf[kc * 2 + 0], qf[kc], s0, 0, 0, 0);
        s1 = __builtin_amdgcn_mfma_f32_32x32x16_bf16(kf[kc * 2 + 1], qf[kc], s1, 0, 0, 0);
    }
    __builtin_amdgcn_s_setprio(0);

    float la0 = 0.f, la1 = 0.f;
    #pragma unroll
    for (int r = 0; r < 16; ++r) {
        float p0 = __builtin_amdgcn_exp2f(s0[r]);
        float p1 = __builtin_amdgcn_exp2f(s1[r]);
        s0[r] = p0; s1[r] = p1;
        la0 += p0; la1 += p1;
    }
    l_ += la0 + la1;

    bf16x8 pa[4];
    {
        #define PKSWAP(dlo, dhi, a0, a1, b0, b1)                                   \
            {   uint wl, wh;                                                       \
                asm("v_cvt_pk_bf16_f32 %0, %1, %2" : "=v"(wl) : "v"(a0), "v"(a1)); \
                asm("v_cvt_pk_bf16_f32 %0, %1, %2" : "=v"(wh) : "v"(b0), "v"(b1)); \
                asm("v_permlane32_swap_b32 %0, %1" : "+v"(wl), "+v"(wh));          \
                dlo = wl; dhi = wh; }
        BF8 t0, t1, t2, t3;
        PKSWAP(t0.u[0], t0.u[2], s0[0],  s0[1],  s0[4],  s0[5]);
        PKSWAP(t0.u[1], t0.u[3], s0[2],  s0[3],  s0[6],  s0[7]);
        PKSWAP(t1.u[0], t1.u[2], s0[8],  s0[9],  s0[12], s0[13]);
        PKSWAP(t1.u[1], t1.u[3], s0[10], s0[11], s0[14], s0[15]);
        PKSWAP(t2.u[0], t2.u[2], s1[0],  s1[1],  s1[4],  s1[5]);
        PKSWAP(t2.u[1], t2.u[3], s1[2],  s1[3],  s1[6],  s1[7]);
        PKSWAP(t3.u[0], t3.u[2], s1[8],  s1[9],  s1[12], s1[13]);
        PKSWAP(t3.u[1], t3.u[3], s1[10], s1[11], s1[14], s1[15]);
        pa[0] = t0.v; pa[1] = t1.v; pa[2] = t2.v; pa[3] = t3.v;
        #undef PKSWAP
    }

    __builtin_amdgcn_s_setprio(1);
    #pragma unroll
    for (int kc = 0; kc < 4; ++kc) {
        o0 = __builtin_amdgcn_mfma_f32_32x32x16_bf16(pa[kc], vf[kc * 2 + 0], o0, 0, 0, 0);
        o1 = __builtin_amdgcn_mfma_f32_32x32x16_bf16(pa[kc], vf[kc * 2 + 1], o1, 0, 0, 0);
    }
    __builtin_amdgcn_s_setprio(0);
}

// ---------------- MFMA flash attention: LDS-free loop, 4-way KV split, zero tail ------
// Block = 512 thr = 8 waves = (qsub = wv&1) x (kvq = wv>>1, quarters of 12 tiles).
// 8 waves = full CU wave budget at 2 waves/SIMD -> exactly 1 block/CU resident;
// grid 768 = EXACTLY 3 uniform rounds (R16's 1.5-round ~25% tail eliminated).
// __launch_bounds__(512,2): 256-reg/wave cap = R16's proven no-spill budget.
// Inner loop byte-identical to R16 (kA/kB prefetch + vC). Merge: 4-way sum via LDS
// (no max-tracking -> plain Sum(l), Sum(o)). TRIPWIRE: WRITE_SIZE ~12 MB.
__global__ __launch_bounds__(512, 2)
void attn19(const ushort* __restrict__ Qb, const ushort* __restrict__ Kbz,
            const ushort* __restrict__ Vtz, const uint64_t* __restrict__ bits2,
            float* __restrict__ out)
{
    const int bid = blockIdx.x;
    const int swz = (bid & 7) * 96 + (bid >> 3);   // 768 blocks, 96/XCD (2 heads/XCD)
    const int h = swz / 48, qg = swz % 48;
    const int tid = threadIdx.x;
    const int wv = tid >> 6, lane = tid & 63;
    const int qsub = wv & 1, kvq = wv >> 1;        // kvq in 0..3
    const int lq = lane & 31, hh = lane >> 5;
    const int qrow0 = (qg * 2 + qsub) * WQ;

    __shared__ __align__(16) float MergeF[2][3][2368];   // 56.8 KB, epilogue only

    bf16x8 qf[4];
    {
        const ushort* qp = Qb + ((size_t)(qrow0 + lq) * NH + h) * DH;
        #pragma unroll
        for (int kc = 0; kc < 4; ++kc)
            qf[kc] = *(const bf16x8*)(qp + kc * 16 + hh * 8);
    }

    f32x16 o0, o1;
    #pragma unroll
    for (int i = 0; i < 16; ++i) { o0[i] = 0.f; o1[i] = 0.f; }
    float l_ = 0.f;

    const int kt0 = kvq * QUART_T;
    const ushort* kbase = Kbz + ((size_t)(h * NKT + kt0)) * 4096;
    const ushort* vbase = Vtz + ((size_t)(h * NKT + kt0)) * 4096;
    const uint64_t* bb = bits2 + (size_t)kt0 * SEQ + qrow0 + lq;

    bf16x8 kA[8], kB[8], vC[8];

    #pragma unroll
    for (int f = 0; f < 8; ++f) kA[f] = ldfrag(kbase, f, lane);
    uint64_t mwA = bb[0];

    for (int it = 0; it < QUART_T; it += 2) {
        {   // process tile it (K in A), prefetch K(it+1) -> B
            const ushort* vt = vbase + (size_t)it * 4096;
            #pragma unroll
            for (int f = 0; f < 8; ++f) vC[f] = ldfrag(vt, f, lane);
            const ushort* kn = kbase + (size_t)(it + 1) * 4096;
            #pragma unroll
            for (int f = 0; f < 8; ++f) kB[f] = ldfrag(kn, f, lane);
            const uint64_t mwB = bb[(size_t)(it + 1) * SEQ];
            process_tile(kA, vC, qf, mwA, hh, o0, o1, l_);
            mwA = mwB;
        }
        {   // process tile it+1 (K in B), prefetch K(it+2) -> A
            const int t2 = (it + 2 < QUART_T) ? it + 2 : QUART_T - 1;
            const ushort* vt = vbase + (size_t)(it + 1) * 4096;
            #pragma unroll
            for (int f = 0; f < 8; ++f) vC[f] = ldfrag(vt, f, lane);
            const ushort* kn = kbase + (size_t)t2 * 4096;
            #pragma unroll
            for (int f = 0; f < 8; ++f) kA[f] = ldfrag(kn, f, lane);
            const uint64_t mwN = bb[(size_t)t2 * SEQ];
            process_tile(kB, vC, qf, mwA, hh, o0, o1, l_);
            mwA = mwN;
        }
    }

    // cross-half l reduction (lanes lq / lq+32 hold complementary partials — R6 lesson)
    {
        float a = l_, b = l_;
        asm("v_permlane32_swap_b32 %0, %1" : "+v"(a), "+v"(b));
        l_ = a + b;
    }

    // ---- 4-way merge of kv-quarters via LDS (generalizes R10 layout; plain sums) ----
    if (kvq >= 1) {
        float* dst = &MergeF[qsub][kvq - 1][0];
        if (hh == 0) dst[64 * 36 + lq] = l_;
        #pragma unroll
        for (int j = 0; j < 4; ++j) {
            float4 t0, t1;
            t0.x = o0[4 * j]; t0.y = o0[4 * j + 1]; t0.z = o0[4 * j + 2]; t0.w = o0[4 * j + 3];
            t1.x = o1[4 * j]; t1.y = o1[4 * j + 1]; t1.z = o1[4 * j + 2]; t1.w = o1[4 * j + 3];
            *(float4*)&dst[lq * 36 + 4 * hh + 8 * j]        = t0;
            *(float4*)&dst[(lq + 32) * 36 + 4 * hh + 8 * j] = t1;
        }
    }
    __syncthreads();
    if (kvq == 0) {
        float l = l_;
        #pragma unroll
        for (int p = 0; p < 3; ++p) l += MergeF[qsub][p][64 * 36 + lq];
        const float inv = (l > 0.f) ? 1.0f / l : 0.f;
        #pragma unroll
        for (int r = 0; r < 16; ++r) {
            const int q_r = (r & 3) + 8 * (r >> 2) + 4 * hh;
            const float ir = __shfl(inv, q_r);
            float a0 = o0[r], a1 = o1[r];
            #pragma unroll
            for (int p = 0; p < 3; ++p) {
                a0 += MergeF[qsub][p][lq * 36 + q_r];
                a1 += MergeF[qsub][p][(lq + 32) * 36 + q_r];
            }
            float* op = out + ((size_t)(qrow0 + q_r) * NH + h) * DH;
            op[lq]      = a0 * ir;
            op[lq + 32] = a1 * ir;
        }
    }
}

// ---------------- fallback (direct int32 mask; only if ws too small) ----------------
__global__ __launch_bounds__(256, 2)
void attn_fb(const float* __restrict__ Q, const float* __restrict__ K,
             const float* __restrict__ V, const int* __restrict__ mask_i32,
             float* __restrict__ out)
{
    const int qtile = blockIdx.x, h = blockIdx.y;
    const int tid  = threadIdx.x;
    const int wv   = tid >> 6, lane = tid & 63;
    const int g    = lane >> 4, c = lane & 15;
    const int qb   = qtile * 64 + wv * 16;

    typedef __attribute__((ext_vector_type(4))) float f32x4;
    __shared__ __align__(16) ushort KbS[KVBLK * 72];
    __shared__ __align__(16) ushort VtS[DH * 72];
    __shared__ __align__(16) ushort PbS[4 * 16 * 72];
    ushort* Pw = &PbS[wv * 16 * 72];

    bf16x8 qa[2];
    {
        const float* qp = Q + ((qb + c) * NH + h) * DH;
        #pragma unroll
        for (int kk = 0; kk < 2; ++kk) {
            BF8 t;
            const float4* pp = (const float4*)(qp + kk * 32 + g * 8);
            float4 f0 = pp[0], f1 = pp[1];
            t.us[0] = f2bf(f0.x * 0.125f); t.us[1] = f2bf(f0.y * 0.125f);
            t.us[2] = f2bf(f0.z * 0.125f); t.us[3] = f2bf(f0.w * 0.125f);
            t.us[4] = f2bf(f1.x * 0.125f); t.us[5] = f2bf(f1.y * 0.125f);
            t.us[6] = f2bf(f1.z * 0.125f); t.us[7] = f2bf(f1.w * 0.125f);
            qa[kk] = t.v;
        }
    }

    f32x4 oacc[4];
    float m_[4], lsum[4];
    #pragma unroll
    for (int nt = 0; nt < 4; ++nt) oacc[nt] = (f32x4){0.f, 0.f, 0.f, 0.f};
    #pragma unroll
    for (int r = 0; r < 4; ++r) { m_[r] = -1e30f; lsum[r] = 0.f; }

    const int srow0 = tid >> 3;
    const int fch   = tid & 7;

    for (int kt = 0; kt < NKT; ++kt) {
        __syncthreads();
        #pragma unroll
        for (int i = 0; i < 2; ++i) {
            const int krow = srow0 + 32 * i;
            const int gofs = ((kt * KVBLK + krow) * NH + h) * DH + fch * 8;
            const float4* kp = (const float4*)(K + gofs);
            const float4* vp = (const float4*)(V + gofs);
            float4 k0 = kp[0], k1 = kp[1];
            float4 v0 = vp[0], v1 = vp[1];
            BF8 kb;
            kb.us[0] = f2bf(k0.x); kb.us[1] = f2bf(k0.y);
            kb.us[2] = f2bf(k0.z); kb.us[3] = f2bf(k0.w);
            kb.us[4] = f2bf(k1.x); kb.us[5] = f2bf(k1.y);
            kb.us[6] = f2bf(k1.z); kb.us[7] = f2bf(k1.w);
            *(uint4*)&KbS[krow * 72 + (fch ^ (krow & 7)) * 8] = kb.u4;
            float vf[8] = {v0.x, v0.y, v0.z, v0.w, v1.x, v1.y, v1.z, v1.w};
            #pragma unroll
            for (int j = 0; j < 8; ++j) {
                const int d = fch * 8 + j;
                VtS[d * 72 + ((krow >> 3) ^ ((d >> 3) & 7)) * 8 + (krow & 7)] = f2bf(vf[j]);
            }
        }
        __syncthreads();

        f32x4 sacc[4];
        #pragma unroll
        for (int nt = 0; nt < 4; ++nt) sacc[nt] = (f32x4){0.f, 0.f, 0.f, 0.f};
        #pragma unroll
        for (int kk = 0; kk < 2; ++kk) {
            #pragma unroll
            for (int nt = 0; nt < 4; ++nt) {
                const int krow = nt * 16 + c;
                bf16x8 kf = *(const bf16x8*)&KbS[krow * 72 + (((g + 4 * kk) ^ (krow & 7))) * 8];
                sacc[nt] = __builtin_amdgcn_mfma_f32_16x16x32_bf16(qa[kk], kf, sacc[nt], 0, 0, 0);
            }
        }

        float pmax[4];
        #pragma unroll
        for (int r = 0; r < 4; ++r) pmax[r] = -1e30f;
        #pragma unroll
        for (int nt = 0; nt < 4; ++nt) {
            #pragma unroll
            for (int r = 0; r < 4; ++r) {
                bool keep = mask_i32[(size_t)(qb + 4 * g + r) * SEQ + kt * KVBLK + nt * 16 + c] != 0;
                float s = keep ? sacc[nt][r] : -1e30f;
                sacc[nt][r] = s;
                pmax[r] = fmaxf(pmax[r], s);
            }
        }
        #pragma unroll
        for (int r = 0; r < 4; ++r) {
            float v = pmax[r];
            v = fmaxf(v, __shfl_xor(v, 1));
            v = fmaxf(v, __shfl_xor(v, 2));
            v = fmaxf(v, __shfl_xor(v, 4));
            v = fmaxf(v, __shfl_xor(v, 8));
            float nm = fmaxf(m_[r], v);
            float alpha = __expf(m_[r] - nm);
            m_[r] = nm;
            lsum[r] *= alpha;
            #pragma unroll
            for (int nt = 0; nt < 4; ++nt) oacc[nt][r] *= alpha;
        }
        #pragma unroll
        for (int nt = 0; nt < 4; ++nt) {
            #pragma unroll
            for (int r = 0; r < 4; ++r) {
                float pv = __expf(sacc[nt][r] - m_[r]);
                lsum[r] += pv;
                const int row = 4 * g + r, col = nt * 16 + c;
                Pw[row * 72 + (((col >> 3) ^ (row & 7))) * 8 + (col & 7)] = f2bf(pv);
            }
        }
        #pragma unroll
        for (int kk = 0; kk < 2; ++kk) {
            bf16x8 pa = *(const bf16x8*)&Pw[c * 72 + (((g + 4 * kk) ^ (c & 7))) * 8];
            #pragma unroll
            for (int nt = 0; nt < 4; ++nt) {
                const int d = nt * 16 + c;
                bf16x8 vb = *(const bf16x8*)&VtS[d * 72 + (((g + 4 * kk) ^ ((d >> 3) & 7))) * 8];
                oacc[nt] = __builtin_amdgcn_mfma_f32_16x16x32_bf16(pa, vb, oacc[nt], 0, 0, 0);
            }
        }
    }

    #pragma unroll
    for (int r = 0; r < 4; ++r) {
        float v = lsum[r];
        v += __shfl_xor(v, 1); v += __shfl_xor(v, 2);
        v += __shfl_xor(v, 4); v += __shfl_xor(v, 8);
        lsum[r] = (v > 0.f) ? 1.0f / v : 0.f;
    }
    #pragma unroll
    for (int nt = 0; nt < 4; ++nt) {
        #pragma unroll
        for (int r = 0; r < 4; ++r) {
            out[((qb + 4 * g + r) * NH + h) * DH + nt * 16 + c] = oacc[nt][r] * lsum[r];
        }
    }
}

extern "C" void kernel_launch(void* const* d_in, const int* in_sizes, int n_in,
                              void* d_out, int out_size, void* d_ws, size_t ws_size,
                              hipStream_t stream) {
    const float* Q    = (const float*)d_in[0];
    const float* K    = (const float*)d_in[1];
    const float* V    = (const float*)d_in[2];
    const void*  mask = d_in[3];
    float* out = (float*)d_out;

    const size_t off_bits = 64;
    const size_t off_qb   = off_bits + (size_t)NWORDS * 8;
    const size_t off_kbz  = off_qb  + (size_t)SEQ * NH * DH * 2;
    const size_t off_vtz  = off_kbz + (size_t)SEQ * NH * DH * 2;
    const size_t need     = off_vtz + (size_t)SEQ * NH * DH * 2;

    if (ws_size >= need) {
        int*      flag = (int*)d_ws;
        uint64_t* bits = (uint64_t*)((char*)d_ws + off_bits);
        ushort*   Qb   = (ushort*)((char*)d_ws + off_qb);
        ushort*   Kbz  = (ushort*)((char*)d_ws + off_kbz);
        ushort*   Vtz  = (ushort*)((char*)d_ws + off_vtz);
        detect_kernel<<<1, 256, 0, stream>>>((const uint32_t*)mask, flag);
        fused_prep<<<2048, 256, 0, stream>>>(K, V, Q, mask, flag, Kbz, Vtz, Qb, bits);
        attn19<<<768, 512, 0, stream>>>(Qb, Kbz, Vtz, bits, out);
    } else {
        attn_fb<<<dim3(NKT, NH), 256, 0, stream>>>(Q, K, V, (const int*)mask, out);
    }
}

// Round 20
// 89.304 us; speedup vs baseline: 1.0962x; 1.0962x over previous
//
#include <hip/hip_runtime.h>
#include <stdint.h>

#define SEQ 3072
#define NH  16
#define DH  64
#define WQ  32
#define KVBLK 64
#define NKT (SEQ / KVBLK)    // 48
#define HALF_T (NKT / 2)     // 24
#define NQT (SEQ / WQ)       // 96
#define NWORDS (SEQ * SEQ / 64)

typedef __attribute__((ext_vector_type(8))) __bf16 bf16x8;
typedef __attribute__((ext_vector_type(16))) float f32x16;

union BF8 { ushort us[8]; uint u[4]; uint4 u4; bf16x8 v; };

__device__ __forceinline__ ushort f2bf(float f) {
    uint u = __builtin_bit_cast(uint, f);
    return (ushort)((u + 0x7FFFu + ((u >> 16) & 1u)) >> 16);
}

#define SCALE_Q (0.125f * 1.44269504f)

// ---------------- fused pre-pass: convert_kv (768) + convert_q (256) + pack (1024) ----
// Pack blocks self-detect the mask dtype from the leading 16 KB (deterministic,
// identical in every block) -> no separate detect launch, no serialization.
__global__ __launch_bounds__(256)
void fused_prep(const float* __restrict__ K, const float* __restrict__ V,
                const float* __restrict__ Q, const void* __restrict__ mask,
                ushort* __restrict__ Kbz, ushort* __restrict__ Vtz,
                ushort* __restrict__ Qb, uint64_t* __restrict__ bits)
{
    const int b = blockIdx.x;
    const int tid = threadIdx.x;

    if (b < 768) {
        // ---------- convert_kv (per-lane fragment order, R12-verified) ----------
        const int kt = b % NKT, h = b / NKT;
        __shared__ float Vf[64][68];
        {
            const int kr = tid >> 2, dc = (tid & 3) * 16;
            const float* vsrc = V + (((size_t)(kt * KVBLK + kr) * NH + h) * DH + dc);
            #pragma unroll
            for (int j = 0; j < 4; ++j) {
                float4 t = *(const float4*)(vsrc + 4 * j);
                Vf[kr][dc + 4 * j + 0] = t.x; Vf[kr][dc + 4 * j + 1] = t.y;
                Vf[kr][dc + 4 * j + 2] = t.z; Vf[kr][dc + 4 * j + 3] = t.w;
            }
        }

        ushort* kout = Kbz + ((size_t)(h * NKT + kt)) * 4096;
        #pragma unroll
        for (int i = 0; i < 2; ++i) {
            const int idx = tid + 256 * i;          // 0..511 = f*64 + l
            const int f = idx >> 6, l = idx & 63;
            const int kc = f >> 1, kh = f & 1;
            const int row = kh * 32 + (l & 31);
            const int kcol = kc * 16 + (l >> 5) * 8;
            const float* ks = K + (((size_t)(kt * KVBLK + row) * NH + h) * DH + kcol);
            float4 a = *(const float4*)(ks);
            float4 c = *(const float4*)(ks + 4);
            BF8 t;
            t.us[0] = f2bf(a.x); t.us[1] = f2bf(a.y); t.us[2] = f2bf(a.z); t.us[3] = f2bf(a.w);
            t.us[4] = f2bf(c.x); t.us[5] = f2bf(c.y); t.us[6] = f2bf(c.z); t.us[7] = f2bf(c.w);
            *(uint4*)(kout + idx * 8) = t.u4;
        }

        __syncthreads();

        ushort* vout = Vtz + ((size_t)(h * NKT + kt)) * 4096;
        #pragma unroll
        for (int i = 0; i < 2; ++i) {
            const int idx = tid + 256 * i;
            const int f = idx >> 6, l = idx & 63;
            const int kc = f >> 1, dh = f & 1;
            const int d = dh * 32 + (l & 31);
            const int kr0 = kc * 16 + (l >> 5) * 8;
            BF8 t;
            #pragma unroll
            for (int j = 0; j < 8; ++j)
                t.us[j] = f2bf(Vf[kr0 + j][d]);
            *(uint4*)(vout + idx * 8) = t.u4;
        }
    } else if (b < 1024) {
        // ---------- convert_q (grid-stride) ----------
        for (int vb = b - 768; vb < SEQ * NH * DH / (256 * 8); vb += 256) {
            int i = (vb * 256 + tid) * 8;
            float4 a = *(const float4*)(Q + i);
            float4 c = *(const float4*)(Q + i + 4);
            BF8 t;
            t.us[0] = f2bf(a.x * SCALE_Q); t.us[1] = f2bf(a.y * SCALE_Q);
            t.us[2] = f2bf(a.z * SCALE_Q); t.us[3] = f2bf(a.w * SCALE_Q);
            t.us[4] = f2bf(c.x * SCALE_Q); t.us[5] = f2bf(c.y * SCALE_Q);
            t.us[6] = f2bf(c.z * SCALE_Q); t.us[7] = f2bf(c.w * SCALE_Q);
            *(uint4*)(Qb + i) = t.u4;
        }
    } else {
        // ---------- local mask-dtype detect (same classification as R1-R19) ----------
        __shared__ int cntA, cntB;
        if (tid == 0) { cntA = 0; cntB = 0; }
        __syncthreads();
        {
            const uint* m32 = (const uint*)mask;
            int a = 0, bb_ = 0;
            #pragma unroll
            for (int i = 0; i < 16; ++i) {
                uint w = m32[tid + i * 256];
                if (w & 0xFFFFFF00u) a = 1;      // high bytes set -> not int32 0/1
                if (w & 0x0000FFFFu) bb_ = 1;    // low half set -> not float 0/1.0
            }
            if (a)  atomicOr(&cntA, 1);
            if (bb_) atomicOr(&cntB, 1);
        }
        __syncthreads();
        const int f = (cntA == 0) ? 1 : ((cntB == 0) ? 2 : 0);

        // ---------- pack -> bits2[kword*SEQ + qrow] (grid-stride) ----------
        for (int vb = b - 1024; vb < SEQ * SEQ / 256; vb += 1024) {
            const int g = vb * 256 + tid;
            bool v;
            if (f == 1)      v = ((const int*)mask)[g] != 0;
            else if (f == 2) v = ((const float*)mask)[g] != 0.0f;
            else             v = ((const unsigned char*)mask)[g] != 0;
            uint64_t bl = __ballot(v);
            if ((tid & 63) == 0) {
                int w = g >> 6;
                int qrow = w / NKT, cw = w % NKT;
                bits[(size_t)cw * SEQ + qrow] = bl;
            }
        }
    }
}

// ---------------- fragment load: global (L2) -> VGPR, no LDS ----------------
__device__ __forceinline__ bf16x8 ldfrag(const ushort* tile, int f, int lane) {
    return *(const bf16x8*)(tile + f * 512 + lane * 8);
}

// ---------------- per-tile math (R10/R12/R15 verified path) ----------------
__device__ __forceinline__ void process_tile(
    const bf16x8 kf[8], const bf16x8 vf[8], const bf16x8 qf[4],
    uint64_t mw, int hh, f32x16& o0, f32x16& o1, float& l_)
{
    const uint64_t mu = mw >> (4 * hh);
    const uint mlo = (uint)mu, mhi = (uint)(mu >> 32);
    f32x16 s0, s1;
    #pragma unroll
    for (int r = 0; r < 16; ++r) {
        const int sh = (r & 3) + 8 * (r >> 2);
        const uint b0 = (mlo >> sh) & 1u;
        const uint b1 = (mhi >> sh) & 1u;
        s0[r] = __builtin_bit_cast(float, (b0 - 1u) & 0xFF800000u);
        s1[r] = __builtin_bit_cast(float, (b1 - 1u) & 0xFF800000u);
    }

    __builtin_amdgcn_s_setprio(1);
    #pragma unroll
    for (int kc = 0; kc < 4; ++kc) {
        s0 = __builtin_amdgcn_mfma_f32_32x32x16_bf16(kf[kc * 2 + 0], qf[kc], s0, 0, 0, 0);
        s1 = __builtin_amdgcn_mfma_f32_32x32x16_bf16(kf[kc * 2 + 1], qf[kc], s1, 0, 0, 0);
    }
    __builtin_amdgcn_s_setprio(0);

    float la0 = 0.f, la1 = 0.f;
    #pragma unroll
    for (int r = 0; r < 16; ++r) {
        float p0 = __builtin_amdgcn_exp2f(s0[r]);
        float p1 = __builtin_amdgcn_exp2f(s1[r]);
        s0[r] = p0; s1[r] = p1;
        la0 += p0; la1 += p1;
    }
    l_ += la0 + la1;

    bf16x8 pa[4];
    {
        #define PKSWAP(dlo, dhi, a0, a1, b0, b1)                                   \
            {   uint wl, wh;                                                       \
                asm("v_cvt_pk_bf16_f32 %0, %1, %2" : "=v"(wl) : "v"(a0), "v"(a1)); \
                asm("v_cvt_pk_bf16_f32 %0, %1, %2" : "=v"(wh) : "v"(b0), "v"(b1)); \
                asm("v_permlane32_swap_b32 %0, %1" : "+v"(wl), "+v"(wh));          \
                dlo = wl; dhi = wh; }
        BF8 t0, t1, t2, t3;
        PKSWAP(t0.u[0], t0.u[2], s0[0],  s0[1],  s0[4],  s0[5]);
        PKSWAP(t0.u[1], t0.u[3], s0[2],  s0[3],  s0[6],  s0[7]);
        PKSWAP(t1.u[0], t1.u[2], s0[8],  s0[9],  s0[12], s0[13]);
        PKSWAP(t1.u[1], t1.u[3], s0[10], s0[11], s0[14], s0[15]);
        PKSWAP(t2.u[0], t2.u[2], s1[0],  s1[1],  s1[4],  s1[5]);
        PKSWAP(t2.u[1], t2.u[3], s1[2],  s1[3],  s1[6],  s1[7]);
        PKSWAP(t3.u[0], t3.u[2], s1[8],  s1[9],  s1[12], s1[13]);
        PKSWAP(t3.u[1], t3.u[3], s1[10], s1[11], s1[14], s1[15]);
        pa[0] = t0.v; pa[1] = t1.v; pa[2] = t2.v; pa[3] = t3.v;
        #undef PKSWAP
    }

    __builtin_amdgcn_s_setprio(1);
    #pragma unroll
    for (int kc = 0; kc < 4; ++kc) {
        o0 = __builtin_amdgcn_mfma_f32_32x32x16_bf16(pa[kc], vf[kc * 2 + 0], o0, 0, 0, 0);
        o1 = __builtin_amdgcn_mfma_f32_32x32x16_bf16(pa[kc], vf[kc * 2 + 1], o1, 0, 0, 0);
    }
    __builtin_amdgcn_s_setprio(0);
}

// ---------------- MFMA flash attention (R16-best, byte-identical): LDS-free loop, ------
// KV-split, merge-only barrier. Block = 256 thr = 4 waves = (qsub, kvh); each wave
// 32 q x 24 kv tiles, no barrier in main loop; 768 blocks, (256,2) = proven no-spill.
__global__ __launch_bounds__(256, 2)
void attn20(const ushort* __restrict__ Qb, const ushort* __restrict__ Kbz,
            const ushort* __restrict__ Vtz, const uint64_t* __restrict__ bits2,
            float* __restrict__ out)
{
    const int bid = blockIdx.x;
    const int swz = (bid & 7) * 96 + (bid >> 3);   // 768 blocks, 96/XCD (2 heads/XCD)
    const int h = swz / 48, qg = swz % 48;
    const int tid = threadIdx.x;
    const int wv = tid >> 6, lane = tid & 63;
    const int qsub = wv & 1, kvh = wv >> 1;
    const int lq = lane & 31, hh = lane >> 5;
    const int qrow0 = (qg * 2 + qsub) * WQ;

    __shared__ __align__(16) float MergeF[2][2368];   // 18.9 KB, epilogue only

    bf16x8 qf[4];
    {
        const ushort* qp = Qb + ((size_t)(qrow0 + lq) * NH + h) * DH;
        #pragma unroll
        for (int kc = 0; kc < 4; ++kc)
            qf[kc] = *(const bf16x8*)(qp + kc * 16 + hh * 8);
    }

    f32x16 o0, o1;
    #pragma unroll
    for (int i = 0; i < 16; ++i) { o0[i] = 0.f; o1[i] = 0.f; }
    float l_ = 0.f;

    const int kt0 = kvh * HALF_T;
    const ushort* kbase = Kbz + ((size_t)(h * NKT + kt0)) * 4096;
    const ushort* vbase = Vtz + ((size_t)(h * NKT + kt0)) * 4096;
    const uint64_t* bb = bits2 + (size_t)kt0 * SEQ + qrow0 + lq;

    bf16x8 kA[8], kB[8], vC[8];

    #pragma unroll
    for (int f = 0; f < 8; ++f) kA[f] = ldfrag(kbase, f, lane);
    uint64_t mwA = bb[0];

    for (int it = 0; it < HALF_T; it += 2) {
        {   // process tile it (K in A), prefetch K(it+1) -> B
            const ushort* vt = vbase + (size_t)it * 4096;
            #pragma unroll
            for (int f = 0; f < 8; ++f) vC[f] = ldfrag(vt, f, lane);
            const ushort* kn = kbase + (size_t)(it + 1) * 4096;
            #pragma unroll
            for (int f = 0; f < 8; ++f) kB[f] = ldfrag(kn, f, lane);
            const uint64_t mwB = bb[(size_t)(it + 1) * SEQ];
            process_tile(kA, vC, qf, mwA, hh, o0, o1, l_);
            mwA = mwB;
        }
        {   // process tile it+1 (K in B), prefetch K(it+2) -> A
            const int t2 = (it + 2 < HALF_T) ? it + 2 : HALF_T - 1;
            const ushort* vt = vbase + (size_t)(it + 1) * 4096;
            #pragma unroll
            for (int f = 0; f < 8; ++f) vC[f] = ldfrag(vt, f, lane);
            const ushort* kn = kbase + (size_t)t2 * 4096;
            #pragma unroll
            for (int f = 0; f < 8; ++f) kA[f] = ldfrag(kn, f, lane);
            const uint64_t mwN = bb[(size_t)t2 * SEQ];
            process_tile(kB, vC, qf, mwA, hh, o0, o1, l_);
            mwA = mwN;
        }
    }

    // cross-half l reduction (lanes lq / lq+32 hold complementary partials — R6 lesson)
    {
        float a = l_, b = l_;
        asm("v_permlane32_swap_b32 %0, %1" : "+v"(a), "+v"(b));
        l_ = a + b;
    }

    // ---- 2-way merge of kv-halves via LDS (R10-verified layout) ----
    float* LMq = &MergeF[qsub][0];
    if (kvh == 1) {
        if (hh == 0) LMq[64 * 36 + lq] = l_;
        #pragma unroll
        for (int j = 0; j < 4; ++j) {
            float4 t0, t1;
            t0.x = o0[4 * j]; t0.y = o0[4 * j + 1]; t0.z = o0[4 * j + 2]; t0.w = o0[4 * j + 3];
            t1.x = o1[4 * j]; t1.y = o1[4 * j + 1]; t1.z = o1[4 * j + 2]; t1.w = o1[4 * j + 3];
            *(float4*)&LMq[lq * 36 + 4 * hh + 8 * j]        = t0;
            *(float4*)&LMq[(lq + 32) * 36 + 4 * hh + 8 * j] = t1;
        }
    }
    __syncthreads();
    if (kvh == 0) {
        const float lB = LMq[64 * 36 + lq];
        const float l = l_ + lB;
        const float inv = (l > 0.f) ? 1.0f / l : 0.f;
        #pragma unroll
        for (int r = 0; r < 16; ++r) {
            const int q_r = (r & 3) + 8 * (r >> 2) + 4 * hh;
            const float ir = __shfl(inv, q_r);
            float* op = out + ((size_t)(qrow0 + q_r) * NH + h) * DH;
            op[lq]      = (o0[r] + LMq[lq * 36 + q_r]) * ir;
            op[lq + 32] = (o1[r] + LMq[(lq + 32) * 36 + q_r]) * ir;
        }
    }
}

// ---------------- fallback (direct int32 mask; only if ws too small) ----------------
__global__ __launch_bounds__(256, 2)
void attn_fb(const float* __restrict__ Q, const float* __restrict__ K,
             const float* __restrict__ V, const int* __restrict__ mask_i32,
             float* __restrict__ out)
{
    const int qtile = blockIdx.x, h = blockIdx.y;
    const int tid  = threadIdx.x;
    const int wv   = tid >> 6, lane = tid & 63;
    const int g    = lane >> 4, c = lane & 15;
    const int qb   = qtile * 64 + wv * 16;

    typedef __attribute__((ext_vector_type(4))) float f32x4;
    __shared__ __align__(16) ushort KbS[KVBLK * 72];
    __shared__ __align__(16) ushort VtS[DH * 72];
    __shared__ __align__(16) ushort PbS[4 * 16 * 72];
    ushort* Pw = &PbS[wv * 16 * 72];

    bf16x8 qa[2];
    {
        const float* qp = Q + ((qb + c) * NH + h) * DH;
        #pragma unroll
        for (int kk = 0; kk < 2; ++kk) {
            BF8 t;
            const float4* pp = (const float4*)(qp + kk * 32 + g * 8);
            float4 f0 = pp[0], f1 = pp[1];
            t.us[0] = f2bf(f0.x * 0.125f); t.us[1] = f2bf(f0.y * 0.125f);
            t.us[2] = f2bf(f0.z * 0.125f); t.us[3] = f2bf(f0.w * 0.125f);
            t.us[4] = f2bf(f1.x * 0.125f); t.us[5] = f2bf(f1.y * 0.125f);
            t.us[6] = f2bf(f1.z * 0.125f); t.us[7] = f2bf(f1.w * 0.125f);
            qa[kk] = t.v;
        }
    }

    f32x4 oacc[4];
    float m_[4], lsum[4];
    #pragma unroll
    for (int nt = 0; nt < 4; ++nt) oacc[nt] = (f32x4){0.f, 0.f, 0.f, 0.f};
    #pragma unroll
    for (int r = 0; r < 4; ++r) { m_[r] = -1e30f; lsum[r] = 0.f; }

    const int srow0 = tid >> 3;
    const int fch   = tid & 7;

    for (int kt = 0; kt < NKT; ++kt) {
        __syncthreads();
        #pragma unroll
        for (int i = 0; i < 2; ++i) {
            const int krow = srow0 + 32 * i;
            const int gofs = ((kt * KVBLK + krow) * NH + h) * DH + fch * 8;
            const float4* kp = (const float4*)(K + gofs);
            const float4* vp = (const float4*)(V + gofs);
            float4 k0 = kp[0], k1 = kp[1];
            float4 v0 = vp[0], v1 = vp[1];
            BF8 kb;
            kb.us[0] = f2bf(k0.x); kb.us[1] = f2bf(k0.y);
            kb.us[2] = f2bf(k0.z); kb.us[3] = f2bf(k0.w);
            kb.us[4] = f2bf(k1.x); kb.us[5] = f2bf(k1.y);
            kb.us[6] = f2bf(k1.z); kb.us[7] = f2bf(k1.w);
            *(uint4*)&KbS[krow * 72 + (fch ^ (krow & 7)) * 8] = kb.u4;
            float vf[8] = {v0.x, v0.y, v0.z, v0.w, v1.x, v1.y, v1.z, v1.w};
            #pragma unroll
            for (int j = 0; j < 8; ++j) {
                const int d = fch * 8 + j;
                VtS[d * 72 + ((krow >> 3) ^ ((d >> 3) & 7)) * 8 + (krow & 7)] = f2bf(vf[j]);
            }
        }
        __syncthreads();

        f32x4 sacc[4];
        #pragma unroll
        for (int nt = 0; nt < 4; ++nt) sacc[nt] = (f32x4){0.f, 0.f, 0.f, 0.f};
        #pragma unroll
        for (int kk = 0; kk < 2; ++kk) {
            #pragma unroll
            for (int nt = 0; nt < 4; ++nt) {
                const int krow = nt * 16 + c;
                bf16x8 kf = *(const bf16x8*)&KbS[krow * 72 + (((g + 4 * kk) ^ (krow & 7))) * 8];
                sacc[nt] = __builtin_amdgcn_mfma_f32_16x16x32_bf16(qa[kk], kf, sacc[nt], 0, 0, 0);
            }
        }

        float pmax[4];
        #pragma unroll
        for (int r = 0; r < 4; ++r) pmax[r] = -1e30f;
        #pragma unroll
        for (int nt = 0; nt < 4; ++nt) {
            #pragma unroll
            for (int r = 0; r < 4; ++r) {
                bool keep = mask_i32[(size_t)(qb + 4 * g + r) * SEQ + kt * KVBLK + nt * 16 + c] != 0;
                float s = keep ? sacc[nt][r] : -1e30f;
                sacc[nt][r] = s;
                pmax[r] = fmaxf(pmax[r], s);
            }
        }
        #pragma unroll
        for (int r = 0; r < 4; ++r) {
            float v = pmax[r];
            v = fmaxf(v, __shfl_xor(v, 1));
            v = fmaxf(v, __shfl_xor(v, 2));
            v = fmaxf(v, __shfl_xor(v, 4));
            v = fmaxf(v, __shfl_xor(v, 8));
            float nm = fmaxf(m_[r], v);
            float alpha = __expf(m_[r] - nm);
            m_[r] = nm;
            lsum[r] *= alpha;
            #pragma unroll
            for (int nt = 0; nt < 4; ++nt) oacc[nt][r] *= alpha;
        }
        #pragma unroll
        for (int nt = 0; nt < 4; ++nt) {
            #pragma unroll
            for (int r = 0; r < 4; ++r) {
                float pv = __expf(sacc[nt][r] - m_[r]);
                lsum[r] += pv;
                const int row = 4 * g + r, col = nt * 16 + c;
                Pw[row * 72 + (((col >> 3) ^ (row & 7))) * 8 + (col & 7)] = f2bf(pv);
            }
        }
        #pragma unroll
        for (int kk = 0; kk < 2; ++kk) {
            bf16x8 pa = *(const bf16x8*)&Pw[c * 72 + (((g + 4 * kk) ^ (c & 7))) * 8];
            #pragma unroll
            for (int nt = 0; nt < 4; ++nt) {
                const int d = nt * 16 + c;
                bf16x8 vb = *(const bf16x8*)&VtS[d * 72 + (((g + 4 * kk) ^ ((d >> 3) & 7))) * 8];
                oacc[nt] = __builtin_amdgcn_mfma_f32_16x16x32_bf16(pa, vb, oacc[nt], 0, 0, 0);
            }
        }
    }

    #pragma unroll
    for (int r = 0; r < 4; ++r) {
        float v = lsum[r];
        v += __shfl_xor(v, 1); v += __shfl_xor(v, 2);
        v += __shfl_xor(v, 4); v += __shfl_xor(v, 8);
        lsum[r] = (v > 0.f) ? 1.0f / v : 0.f;
    }
    #pragma unroll
    for (int nt = 0; nt < 4; ++nt) {
        #pragma unroll
        for (int r = 0; r < 4; ++r) {
            out[((qb + 4 * g + r) * NH + h) * DH + nt * 16 + c] = oacc[nt][r] * lsum[r];
        }
    }
}

extern "C" void kernel_launch(void* const* d_in, const int* in_sizes, int n_in,
                              void* d_out, int out_size, void* d_ws, size_t ws_size,
                              hipStream_t stream) {
    const float* Q    = (const float*)d_in[0];
    const float* K    = (const float*)d_in[1];
    const float* V    = (const float*)d_in[2];
    const void*  mask = d_in[3];
    float* out = (float*)d_out;

    const size_t off_bits = 64;
    const size_t off_qb   = off_bits + (size_t)NWORDS * 8;
    const size_t off_kbz  = off_qb  + (size_t)SEQ * NH * DH * 2;
    const size_t off_vtz  = off_kbz + (size_t)SEQ * NH * DH * 2;
    const size_t need     = off_vtz + (size_t)SEQ * NH * DH * 2;

    if (ws_size >= need) {
        uint64_t* bits = (uint64_t*)((char*)d_ws + off_bits);
        ushort*   Qb   = (ushort*)((char*)d_ws + off_qb);
        ushort*   Kbz  = (ushort*)((char*)d_ws + off_kbz);
        ushort*   Vtz  = (ushort*)((char*)d_ws + off_vtz);
        fused_prep<<<2048, 256, 0, stream>>>(K, V, Q, mask, Kbz, Vtz, Qb, bits);
        attn20<<<NQT * NH / 2, 256, 0, stream>>>(Qb, Kbz, Vtz, bits, out);
    } else {
        attn_fb<<<dim3(NKT, NH), 256, 0, stream>>>(Q, K, V, (const int*)mask, out);
    }
}